// Round 1
// baseline (336.451 us; speedup 1.0000x reference)
//
#include <hip/hip_runtime.h>
#include <hip/hip_bf16.h>
#include <math.h>

typedef unsigned short u16;
typedef short short8 __attribute__((ext_vector_type(8)));
typedef float floatx4 __attribute__((ext_vector_type(4)));

#define B_   2
#define S_   2048
#define DM_  2048
#define H_   16
#define KVH_ 4
#define HD_  128

__device__ __forceinline__ float bf2f(u16 v) {
  union { unsigned int u; float f; } x; x.u = ((unsigned int)v) << 16; return x.f;
}
__device__ __forceinline__ u16 f2bf(float f) {
  union { float f; unsigned int u; } x; x.f = f;
  unsigned int u = x.u;
  u += 0x7FFFu + ((u >> 16) & 1u);   // RNE; inputs finite
  return (u16)(u >> 16);
}

// async 16B global->LDS (lds dest = wave-uniform base + lane*16)
#define GLDS16(gp, lp) __builtin_amdgcn_global_load_lds( \
    (const __attribute__((address_space(1))) unsigned int*)(const void*)(gp), \
    (__attribute__((address_space(3))) unsigned int*)(void*)(lp), 16, 0, 0)

// ---------------------------------------------------------------------------
// k_prep: pack_x (blocks 0..8191) + 4 weight transposes (blocks 8192..18431)
// merged into one launch (block-uniform branching).
// ---------------------------------------------------------------------------
__global__ __launch_bounds__(256) void k_prep(
    const float* __restrict__ x, const float* __restrict__ wq,
    const float* __restrict__ wk, const float* __restrict__ wv,
    const float* __restrict__ wo,
    u16* __restrict__ x_bf, u16* __restrict__ wqkv_t, u16* __restrict__ wo_t)
{
  int bx = blockIdx.x;
  if (bx < 8192) {                       // x -> bf16, 4 elems/thread
    int i = bx * 256 + threadIdx.x;
    const float4 v = ((const float4*)x)[i];
    u16 o[4] = { f2bf(v.x), f2bf(v.y), f2bf(v.z), f2bf(v.w) };
    *(unsigned long long*)(x_bf + (size_t)i * 4) = *(unsigned long long*)o;
    return;
  }
  bx -= 8192;
  const float* src; u16* dst; int C, cb;
  if (bx < 4096)      { src = wq; dst = wqkv_t; C = 2048; cb = 64; }
  else if (bx < 5120) { bx -= 4096; src = wk; dst = wqkv_t + (size_t)2048 * 2048; C = 512; cb = 16; }
  else if (bx < 6144) { bx -= 5120; src = wv; dst = wqkv_t + (size_t)2560 * 2048; C = 512; cb = 16; }
  else                { bx -= 6144; src = wo; dst = wo_t; C = 2048; cb = 64; }
  const int R = 2048;
  int c0 = (bx % cb) * 32, r0 = (bx / cb) * 32;
  __shared__ float tile[32][33];
  int tx = threadIdx.x & 31, ty = threadIdx.x >> 5;
#pragma unroll
  for (int j = 0; j < 4; j++)
    tile[ty * 4 + j][tx] = src[(size_t)(r0 + ty * 4 + j) * C + c0 + tx];
  __syncthreads();
#pragma unroll
  for (int j = 0; j < 4; j++)
    dst[(size_t)(c0 + ty * 4 + j) * R + r0 + tx] = f2bf(tile[tx][ty * 4 + j]);
}

// ---------------------------------------------------------------------------
// GEMM: C[M][N] = A[M][K] * Bt[N][K]^T   (bf16 in, f32 accum, f32/bf16 out)
// 128x128 tile, BK=64 (32 KB LDS): 32 MFMA per barrier pair (AITER ratio).
// LDS row = 8 chunks of 16B; swizzle chunk ^ (row&7) kills bank conflicts.
// ---------------------------------------------------------------------------
__global__ __launch_bounds__(256, 3) void k_gemm_bt(
    const u16* __restrict__ A, const u16* __restrict__ Bt,
    void* __restrict__ Cout, int M, int N, int K, int c_bf16)
{
  __shared__ u16 As[128 * 64];
  __shared__ u16 Bs[128 * 64];
  int tid = threadIdx.x;
  int lane = tid & 63;
  int quad = lane >> 4, l16 = lane & 15;
  int wid = tid >> 6;
  int m0 = blockIdx.y * 128, n0 = blockIdx.x * 128;
  int wm = (wid >> 1) * 64, wn = (wid & 1) * 64;

  floatx4 acc[4][4] = {};

  // staging: c = j*256 + tid -> row = c>>3 (j adds 32 rows; row&7 invariant),
  // LDS chunkpos = c&7 holds global chunk (c&7) ^ (row&7)
  int srow = tid >> 3;
  int gjc0 = (tid & 7) ^ (srow & 7);
  const u16* Ap = A + (size_t)(m0 + srow) * K + gjc0 * 8;
  const u16* Bp = Bt + (size_t)(n0 + srow) * K + gjc0 * 8;
  u16* AsW = As + tid * 8;
  u16* BsW = Bs + tid * 8;

  for (int kt = 0; kt < K; kt += 64) {
    __syncthreads();                     // protect LDS from prev iter readers
#pragma unroll
    for (int j = 0; j < 4; j++) {
      GLDS16(Ap + (size_t)(j * 32) * K, AsW + j * 2048);
      GLDS16(Bp + (size_t)(j * 32) * K, BsW + j * 2048);
    }
    Ap += 64; Bp += 64;
    __syncthreads();                     // drains vmcnt(0)

#pragma unroll
    for (int ks = 0; ks < 2; ks++) {
      short8 af[4], bfv[4];
#pragma unroll
      for (int mi = 0; mi < 4; mi++) {
        int row = wm + mi * 16 + l16;
        af[mi] = *(const short8*)&As[row * 64 + (((ks * 4 + quad) ^ (row & 7)) * 8)];
      }
#pragma unroll
      for (int ni = 0; ni < 4; ni++) {
        int row = wn + ni * 16 + l16;
        bfv[ni] = *(const short8*)&Bs[row * 64 + (((ks * 4 + quad) ^ (row & 7)) * 8)];
      }
#pragma unroll
      for (int mi = 0; mi < 4; mi++)
#pragma unroll
        for (int ni = 0; ni < 4; ni++)
          acc[mi][ni] = __builtin_amdgcn_mfma_f32_16x16x32_bf16(
              af[mi], bfv[ni], acc[mi][ni], 0, 0, 0);
    }
  }

#pragma unroll
  for (int mi = 0; mi < 4; mi++)
#pragma unroll
    for (int ni = 0; ni < 4; ni++)
#pragma unroll
      for (int r = 0; r < 4; r++) {
        int row = m0 + wm + mi * 16 + quad * 4 + r;
        int col = n0 + wn + ni * 16 + l16;
        float v = acc[mi][ni][r];
        if (c_bf16) ((u16*)Cout)[(size_t)row * N + col] = f2bf(v);
        else        ((float*)Cout)[(size_t)row * N + col] = v;
      }
}

// ---------------------------------------------------------------------------
// k_post: RMSNorm+RoPE (blocks 0..4095) + pack_vt (blocks 4096..6143) merged.
// ---------------------------------------------------------------------------
__global__ __launch_bounds__(256) void k_post(
    const u16* __restrict__ C1, const float* __restrict__ qs,
    const float* __restrict__ ks, u16* __restrict__ qr, u16* __restrict__ kr,
    u16* __restrict__ vt)
{
  int bx = blockIdx.x;
  if (bx < 4096) {                       // rmsnorm + rope
    int m = bx;
    int lane = threadIdx.x & 63, wid = threadIdx.x >> 6;
    int pos = m & (S_ - 1);
    float ts = powf(10000.0f, (float)lane * (1.0f / 64.0f));
    float ang = (float)pos / ts;
    float sn = sinf(ang), cs = cosf(ang);
    for (int r = wid; r < H_ + KVH_; r += 4) {
      bool isq = r < H_;
      const u16* src = C1 + (size_t)m * 3072 + (isq ? r * HD_ : DM_ + (r - H_) * HD_);
      float x1 = bf2f(src[lane]), x2 = bf2f(src[lane + 64]);
      float ss = x1 * x1 + x2 * x2;
#pragma unroll
      for (int d = 1; d < 64; d <<= 1) ss += __shfl_xor(ss, d);
      float rs = rsqrtf(ss * (1.0f / 128.0f) + 1e-6f);
      const float* sc = isq ? qs : ks;
      float y1 = x1 * rs * sc[lane];
      float y2 = x2 * rs * sc[lane + 64];
      float o1 = y1 * cs - y2 * sn;
      float o2 = y2 * cs + y1 * sn;
      if (isq) { o1 *= 0.088388347648318447f; o2 *= 0.088388347648318447f; }
      u16* dst = isq ? (qr + ((size_t)m * H_ + r) * HD_)
                     : (kr + ((size_t)m * KVH_ + (r - H_)) * HD_);
      dst[lane]      = f2bf(o1);
      dst[lane + 64] = f2bf(o2);
    }
    return;
  }
  bx -= 4096;                            // pack_vt: decode 64 x 4 x 8
  int sx = bx & 63, rest = bx >> 6;
  int hy = rest & 3, bk = rest >> 2;
  int s0 = sx * 32, h0 = hy * 32;
  int b = bk >> 2, kv = bk & 3;
  __shared__ u16 tile[32][33];
  int tx = threadIdx.x & 31, ty = threadIdx.x >> 5;
#pragma unroll
  for (int j = 0; j < 4; j++)
    tile[ty * 4 + j][tx] =
        C1[(size_t)(b * S_ + s0 + ty * 4 + j) * 3072 + 2560 + kv * HD_ + h0 + tx];
  __syncthreads();
#pragma unroll
  for (int j = 0; j < 4; j++)
    vt[((size_t)bk * HD_ + h0 + ty * 4 + j) * S_ + s0 + tx] = tile[tx][ty * 4 + j];
}

// ---------------------------------------------------------------------------
// Flash attention, register-prefetch pipeline + global longest-first order.
// FIXED-MAX softmax (Cauchy-Schwarz bound |score| <= 11.32 post-RMSNorm).
// v2: 2 waves x 32 q-rows (was 4 x 16) -> every K/V LDS fragment read feeds
//     TWO MFMAs; LDS read traffic per output row halved (LDS-BW-bound fix).
//     Ps XOR-swizzled [32][64] (GEMM-proven chunk^(row&7)); LDS = 40 KB
//     exactly -> 4 blocks/CU. s_setprio(1) around MFMA clusters (m191).
// ---------------------------------------------------------------------------
__global__ __launch_bounds__(128, 2) void k_flash(
    const u16* __restrict__ qr, const u16* __restrict__ kr,
    const u16* __restrict__ vt, u16* __restrict__ att)
{
  __shared__ u16 Ks[64 * 128];       // [s][hd]  16B-chunk ^ (row&15)
  __shared__ u16 Vt[128 * 64];       // [hd][s]  16B-chunk ^ (row&7)
  __shared__ u16 Ps[2][32 * 64];     // per-wave P tile, chunk ^ (row&7)
  int tid = threadIdx.x, lane = tid & 63, wid = tid >> 6;
  int quad = lane >> 4, l16 = lane & 15;
  int bx = blockIdx.x;
  int it = 31 - (bx >> 5);           // global longest-first
  int hb = bx & 31;
  int h = hb & 15, b = hb >> 4;
  int kvh = h >> 2;                  // G = 4
  int q0 = it * 64;

  // Q fragments: wave covers 32 rows (m = 0,1)
  short8 qf[2][4];
#pragma unroll
  for (int m = 0; m < 2; m++) {
    const u16* qb = qr + ((size_t)(b * S_ + q0 + wid * 32 + m * 16 + l16) * H_ + h) * HD_;
#pragma unroll
    for (int kk = 0; kk < 4; kk++)
      qf[m][kk] = *(const short8*)(qb + kk * 32 + quad * 8);
  }

  // staging: 128 threads. K: thread -> (row = j*8 + (tid>>4), slot = tid&15),
  // global chunk = slot ^ (row&15) = gK ^ ((j&1)<<3).  V: (row = j*16 +
  // (tid>>3), slot = tid&7), global chunk = gV (row&7 j-invariant).
  int gK = (tid & 15) ^ (tid >> 4);
  int gV = (tid & 7) ^ ((tid >> 3) & 7);
  const u16* kp = kr + ((size_t)(b * S_ + (tid >> 4)) * KVH_ + kvh) * HD_;
  const u16* vp = vt + ((size_t)(b * KVH_ + kvh) * HD_ + (tid >> 3)) * S_ + gV * 8;

  short8 pk[8], pv[8];
#pragma unroll
  for (int j = 0; j < 8; j++) {
    pk[j] = *(const short8*)(kp + (size_t)(j * 8) * KVH_ * HD_ + (gK ^ ((j & 1) << 3)) * 8);
    pv[j] = *(const short8*)(vp + (size_t)(j * 16) * S_);
  }

  floatx4 accO[2][8] = {};
  float lp[2][4] = {};
  u16* PsW = &Ps[wid][0];

  const float LOG2E = 1.4426950408889634f;
  const float MBIAS = -12.5f * 1.4426950408889634f;

  for (int kt = 0; kt <= it; kt++) {
    int k0 = kt * 64;
#pragma unroll
    for (int j = 0; j < 8; j++) {
      *(short8*)&Ks[(j * 128 + tid) * 8] = pk[j];
      *(short8*)&Vt[(j * 128 + tid) * 8] = pv[j];
    }
    __syncthreads();

    if (kt < it) {
      kp += (size_t)64 * KVH_ * HD_;
      vp += 64;
#pragma unroll
      for (int j = 0; j < 8; j++) {
        pk[j] = *(const short8*)(kp + (size_t)(j * 8) * KVH_ * HD_ + (gK ^ ((j & 1) << 3)) * 8);
        pv[j] = *(const short8*)(vp + (size_t)(j * 16) * S_);
      }
    }

    floatx4 sacc[2][4] = {};
    __builtin_amdgcn_s_setprio(1);
#pragma unroll
    for (int kk = 0; kk < 4; kk++) {
      short8 kf[4];
#pragma unroll
      for (int nt = 0; nt < 4; nt++) {
        int row = nt * 16 + l16;
        kf[nt] = *(const short8*)&Ks[row * 128 + (((kk * 4 + quad) ^ (row & 15)) * 8)];
      }
#pragma unroll
      for (int nt = 0; nt < 4; nt++) {
        sacc[0][nt] = __builtin_amdgcn_mfma_f32_16x16x32_bf16(qf[0][kk], kf[nt], sacc[0][nt], 0, 0, 0);
        sacc[1][nt] = __builtin_amdgcn_mfma_f32_16x16x32_bf16(qf[1][kk], kf[nt], sacc[1][nt], 0, 0, 0);
      }
    }
    __builtin_amdgcn_s_setprio(0);

    bool diag = (kt == it);
#pragma unroll
    for (int m = 0; m < 2; m++)
#pragma unroll
      for (int r = 0; r < 4; r++) {
        int prow = m * 16 + quad * 4 + r;
        int qrow = q0 + wid * 32 + prow;
        float rsum = 0.f;
#pragma unroll
        for (int nt = 0; nt < 4; nt++) {
          float p = __builtin_amdgcn_exp2f(fmaf(sacc[m][nt][r], LOG2E, MBIAS));
          if (diag && (k0 + nt * 16 + l16) > qrow) p = 0.f;
          rsum += p;
          // element (prow, col = nt*16+l16): chunk = col>>3, slot = chunk^(prow&7)
          PsW[prow * 64 + (((nt * 2 + (l16 >> 3)) ^ (prow & 7)) * 8) + (l16 & 7)] = f2bf(p);
        }
        lp[m][r] += rsum;
      }

    __builtin_amdgcn_s_setprio(1);
#pragma unroll
    for (int kk = 0; kk < 2; kk++) {
      short8 pf[2];
#pragma unroll
      for (int m = 0; m < 2; m++) {
        int prow = m * 16 + l16;
        pf[m] = *(const short8*)&PsW[prow * 64 + (((kk * 4 + quad) ^ (prow & 7)) * 8)];
      }
#pragma unroll
      for (int ht = 0; ht < 8; ht++) {
        int row = ht * 16 + l16;
        short8 vf = *(const short8*)&Vt[row * 64 + (((kk * 4 + quad) ^ (row & 7)) * 8)];
        accO[0][ht] = __builtin_amdgcn_mfma_f32_16x16x32_bf16(pf[0], vf, accO[0][ht], 0, 0, 0);
        accO[1][ht] = __builtin_amdgcn_mfma_f32_16x16x32_bf16(pf[1], vf, accO[1][ht], 0, 0, 0);
      }
    }
    __builtin_amdgcn_s_setprio(0);
    __syncthreads();
  }

#pragma unroll
  for (int m = 0; m < 2; m++)
#pragma unroll
    for (int r = 0; r < 4; r++) {
#pragma unroll
      for (int d = 1; d < 16; d <<= 1) lp[m][r] += __shfl_xor(lp[m][r], d);
      lp[m][r] = 1.0f / lp[m][r];
    }

#pragma unroll
  for (int m = 0; m < 2; m++)
#pragma unroll
    for (int ht = 0; ht < 8; ht++)
#pragma unroll
      for (int r = 0; r < 4; r++) {
        int row = q0 + wid * 32 + m * 16 + quad * 4 + r;
        att[((size_t)(b * S_ + row) * H_ + h) * HD_ + ht * 16 + l16] =
            f2bf(accO[m][ht][r] * lp[m][r]);
      }
}

// ---------------------------------------------------------------------------
extern "C" void kernel_launch(void* const* d_in, const int* in_sizes, int n_in,
                              void* d_out, int out_size, void* d_ws, size_t ws_size,
                              hipStream_t stream)
{
  const float* x  = (const float*)d_in[0];   // [B,S,DM] f32
  const float* wq = (const float*)d_in[1];   // [DM, H*HD] f32
  const float* wk = (const float*)d_in[2];   // [DM, KV*HD] f32
  const float* wv = (const float*)d_in[3];   // [DM, KV*HD] f32
  const float* wo = (const float*)d_in[4];   // [H*HD, DM] f32
  const float* qs = (const float*)d_in[5];   // [HD] f32
  const float* ks = (const float*)d_in[6];   // [HD] f32

  char* ws = (char*)d_ws;
  size_t off = 0;
  u16* x_bf   = (u16*)(ws + off); off += (size_t)4096 * 2048 * 2;   // x bf16
  u16* wqkv_t = (u16*)(ws + off); off += (size_t)3072 * 2048 * 2;   // [3072][2048]
  u16* wo_t   = (u16*)(ws + off); off += (size_t)2048 * 2048 * 2;   // [2048][2048]
  u16* C1     = (u16*)(ws + off); off += (size_t)4096 * 3072 * 2;   // qkv bf16
  u16* q_rope = (u16*)(ws + off); off += (size_t)4096 * 16 * 128 * 2;
  u16* k_rope = (u16*)(ws + off); off += (size_t)4096 * 4 * 128 * 2;
  u16* vt     = (u16*)(ws + off); off += (size_t)8 * 128 * 2048 * 2;
  u16* att    = (u16*)(ws + off); off += (size_t)4096 * 2048 * 2;

  // pack x + all weight transposes, one launch
  k_prep<<<dim3(18432), 256, 0, stream>>>(x, wq, wk, wv, wo, x_bf, wqkv_t, wo_t);

  // qkv = x @ [wq|wk|wv]  (bf16 out)
  k_gemm_bt<<<dim3(24, 32), 256, 0, stream>>>(x_bf, wqkv_t, C1, 4096, 3072, 2048, 1);

  // rmsnorm+rope + v-transpose, one launch
  k_post<<<dim3(6144), 256, 0, stream>>>(C1, qs, ks, q_rope, k_rope, vt);

  // causal flash: 1024 blocks x 2 waves (32 q-rows/wave), longest-first
  k_flash<<<dim3(1024), 128, 0, stream>>>(q_rope, k_rope, vt, att);

  // out = att @ wo  (f32 out, matching reference output dtype)
  k_gemm_bt<<<dim3(16, 32), 256, 0, stream>>>(att, wo_t, d_out, 4096, 2048, 2048, 0);

  (void)in_sizes; (void)n_in; (void)out_size; (void)ws_size;
}

// Round 2
// 302.927 us; speedup vs baseline: 1.1107x; 1.1107x over previous
//
#include <hip/hip_runtime.h>
#include <hip/hip_bf16.h>
#include <math.h>

typedef unsigned short u16;
typedef short short8 __attribute__((ext_vector_type(8)));
typedef float floatx4 __attribute__((ext_vector_type(4)));

#define B_   2
#define S_   2048
#define DM_  2048
#define H_   16
#define KVH_ 4
#define HD_  128

__device__ __forceinline__ float bf2f(u16 v) {
  union { unsigned int u; float f; } x; x.u = ((unsigned int)v) << 16; return x.f;
}
__device__ __forceinline__ u16 f2bf(float f) {
  union { float f; unsigned int u; } x; x.f = f;
  unsigned int u = x.u;
  u += 0x7FFFu + ((u >> 16) & 1u);   // RNE; inputs finite
  return (u16)(u >> 16);
}

// async 16B global->LDS (lds dest = wave-uniform base + lane*16)
#define GLDS16(gp, lp) __builtin_amdgcn_global_load_lds( \
    (const __attribute__((address_space(1))) unsigned int*)(const void*)(gp), \
    (__attribute__((address_space(3))) unsigned int*)(void*)(lp), 16, 0, 0)

// ---------------------------------------------------------------------------
// k_prep: pack_x (blocks 0..8191) + 4 weight transposes (blocks 8192..18431)
// merged into one launch (block-uniform branching).
// ---------------------------------------------------------------------------
__global__ __launch_bounds__(256) void k_prep(
    const float* __restrict__ x, const float* __restrict__ wq,
    const float* __restrict__ wk, const float* __restrict__ wv,
    const float* __restrict__ wo,
    u16* __restrict__ x_bf, u16* __restrict__ wqkv_t, u16* __restrict__ wo_t)
{
  int bx = blockIdx.x;
  if (bx < 8192) {                       // x -> bf16, 4 elems/thread
    int i = bx * 256 + threadIdx.x;
    const float4 v = ((const float4*)x)[i];
    u16 o[4] = { f2bf(v.x), f2bf(v.y), f2bf(v.z), f2bf(v.w) };
    *(unsigned long long*)(x_bf + (size_t)i * 4) = *(unsigned long long*)o;
    return;
  }
  bx -= 8192;
  const float* src; u16* dst; int C, cb;
  if (bx < 4096)      { src = wq; dst = wqkv_t; C = 2048; cb = 64; }
  else if (bx < 5120) { bx -= 4096; src = wk; dst = wqkv_t + (size_t)2048 * 2048; C = 512; cb = 16; }
  else if (bx < 6144) { bx -= 5120; src = wv; dst = wqkv_t + (size_t)2560 * 2048; C = 512; cb = 16; }
  else                { bx -= 6144; src = wo; dst = wo_t; C = 2048; cb = 64; }
  const int R = 2048;
  int c0 = (bx % cb) * 32, r0 = (bx / cb) * 32;
  __shared__ float tile[32][33];
  int tx = threadIdx.x & 31, ty = threadIdx.x >> 5;
#pragma unroll
  for (int j = 0; j < 4; j++)
    tile[ty * 4 + j][tx] = src[(size_t)(r0 + ty * 4 + j) * C + c0 + tx];
  __syncthreads();
#pragma unroll
  for (int j = 0; j < 4; j++)
    dst[(size_t)(c0 + ty * 4 + j) * R + r0 + tx] = f2bf(tile[tx][ty * 4 + j]);
}

// ---------------------------------------------------------------------------
// GEMM: C[M][N] = A[M][K] * Bt[N][K]^T   (bf16 in, f32 accum, f32/bf16 out)
// 128x128 tile, BK=64 (32 KB LDS): 32 MFMA per barrier pair (AITER ratio).
// LDS row = 8 chunks of 16B; swizzle chunk ^ (row&7) kills bank conflicts.
// ---------------------------------------------------------------------------
__global__ __launch_bounds__(256, 3) void k_gemm_bt(
    const u16* __restrict__ A, const u16* __restrict__ Bt,
    void* __restrict__ Cout, int M, int N, int K, int c_bf16)
{
  __shared__ u16 As[128 * 64];
  __shared__ u16 Bs[128 * 64];
  int tid = threadIdx.x;
  int lane = tid & 63;
  int quad = lane >> 4, l16 = lane & 15;
  int wid = tid >> 6;
  int m0 = blockIdx.y * 128, n0 = blockIdx.x * 128;
  int wm = (wid >> 1) * 64, wn = (wid & 1) * 64;

  floatx4 acc[4][4] = {};

  // staging: c = j*256 + tid -> row = c>>3 (j adds 32 rows; row&7 invariant),
  // LDS chunkpos = c&7 holds global chunk (c&7) ^ (row&7)
  int srow = tid >> 3;
  int gjc0 = (tid & 7) ^ (srow & 7);
  const u16* Ap = A + (size_t)(m0 + srow) * K + gjc0 * 8;
  const u16* Bp = Bt + (size_t)(n0 + srow) * K + gjc0 * 8;
  u16* AsW = As + tid * 8;
  u16* BsW = Bs + tid * 8;

  for (int kt = 0; kt < K; kt += 64) {
    __syncthreads();                     // protect LDS from prev iter readers
#pragma unroll
    for (int j = 0; j < 4; j++) {
      GLDS16(Ap + (size_t)(j * 32) * K, AsW + j * 2048);
      GLDS16(Bp + (size_t)(j * 32) * K, BsW + j * 2048);
    }
    Ap += 64; Bp += 64;
    __syncthreads();                     // drains vmcnt(0)

#pragma unroll
    for (int ks = 0; ks < 2; ks++) {
      short8 af[4], bfv[4];
#pragma unroll
      for (int mi = 0; mi < 4; mi++) {
        int row = wm + mi * 16 + l16;
        af[mi] = *(const short8*)&As[row * 64 + (((ks * 4 + quad) ^ (row & 7)) * 8)];
      }
#pragma unroll
      for (int ni = 0; ni < 4; ni++) {
        int row = wn + ni * 16 + l16;
        bfv[ni] = *(const short8*)&Bs[row * 64 + (((ks * 4 + quad) ^ (row & 7)) * 8)];
      }
#pragma unroll
      for (int mi = 0; mi < 4; mi++)
#pragma unroll
        for (int ni = 0; ni < 4; ni++)
          acc[mi][ni] = __builtin_amdgcn_mfma_f32_16x16x32_bf16(
              af[mi], bfv[ni], acc[mi][ni], 0, 0, 0);
    }
  }

#pragma unroll
  for (int mi = 0; mi < 4; mi++)
#pragma unroll
    for (int ni = 0; ni < 4; ni++)
#pragma unroll
      for (int r = 0; r < 4; r++) {
        int row = m0 + wm + mi * 16 + quad * 4 + r;
        int col = n0 + wn + ni * 16 + l16;
        float v = acc[mi][ni][r];
        if (c_bf16) ((u16*)Cout)[(size_t)row * N + col] = f2bf(v);
        else        ((float*)Cout)[(size_t)row * N + col] = v;
      }
}

// ---------------------------------------------------------------------------
// k_post: RMSNorm+RoPE (blocks 0..4095) + pack_vt (blocks 4096..6143) merged.
// ---------------------------------------------------------------------------
__global__ __launch_bounds__(256) void k_post(
    const u16* __restrict__ C1, const float* __restrict__ qs,
    const float* __restrict__ ks, u16* __restrict__ qr, u16* __restrict__ kr,
    u16* __restrict__ vt)
{
  int bx = blockIdx.x;
  if (bx < 4096) {                       // rmsnorm + rope
    int m = bx;
    int lane = threadIdx.x & 63, wid = threadIdx.x >> 6;
    int pos = m & (S_ - 1);
    float ts = powf(10000.0f, (float)lane * (1.0f / 64.0f));
    float ang = (float)pos / ts;
    float sn = sinf(ang), cs = cosf(ang);
    for (int r = wid; r < H_ + KVH_; r += 4) {
      bool isq = r < H_;
      const u16* src = C1 + (size_t)m * 3072 + (isq ? r * HD_ : DM_ + (r - H_) * HD_);
      float x1 = bf2f(src[lane]), x2 = bf2f(src[lane + 64]);
      float ss = x1 * x1 + x2 * x2;
#pragma unroll
      for (int d = 1; d < 64; d <<= 1) ss += __shfl_xor(ss, d);
      float rs = rsqrtf(ss * (1.0f / 128.0f) + 1e-6f);
      const float* sc = isq ? qs : ks;
      float y1 = x1 * rs * sc[lane];
      float y2 = x2 * rs * sc[lane + 64];
      float o1 = y1 * cs - y2 * sn;
      float o2 = y2 * cs + y1 * sn;
      if (isq) { o1 *= 0.088388347648318447f; o2 *= 0.088388347648318447f; }
      u16* dst = isq ? (qr + ((size_t)m * H_ + r) * HD_)
                     : (kr + ((size_t)m * KVH_ + (r - H_)) * HD_);
      dst[lane]      = f2bf(o1);
      dst[lane + 64] = f2bf(o2);
    }
    return;
  }
  bx -= 4096;                            // pack_vt: decode 64 x 4 x 8
  int sx = bx & 63, rest = bx >> 6;
  int hy = rest & 3, bk = rest >> 2;
  int s0 = sx * 32, h0 = hy * 32;
  int b = bk >> 2, kv = bk & 3;
  __shared__ u16 tile[32][33];
  int tx = threadIdx.x & 31, ty = threadIdx.x >> 5;
#pragma unroll
  for (int j = 0; j < 4; j++)
    tile[ty * 4 + j][tx] =
        C1[(size_t)(b * S_ + s0 + ty * 4 + j) * 3072 + 2560 + kv * HD_ + h0 + tx];
  __syncthreads();
#pragma unroll
  for (int j = 0; j < 4; j++)
    vt[((size_t)bk * HD_ + h0 + ty * 4 + j) * S_ + s0 + tx] = tile[tx][ty * 4 + j];
}

// ---------------------------------------------------------------------------
// Flash attention v3: 4 waves x 32 q-rows (block = 128 q-rows), KV tile 64.
// Combines v1's co-residency (8 waves/CU = 2/SIMD) with v2's K/V-fragment
// amortization (each LDS fragment read feeds 2 MFMAs). v2's 2-wave blocks
// starved the SIMDs (1 wave/SIMD -> 120us); this restores TLP.
// FIXED-MAX softmax (Cauchy-Schwarz bound |score| <= 11.32 post-RMSNorm).
// Per-wave causal tile classes: full (kt < ktd), diag (kt == ktd),
// fully-masked (kt > ktd, skip compute; staging+barriers only).
// ---------------------------------------------------------------------------
__global__ __launch_bounds__(256, 2) void k_flash(
    const u16* __restrict__ qr, const u16* __restrict__ kr,
    const u16* __restrict__ vt, u16* __restrict__ att)
{
  __shared__ u16 Ks[64 * 128];       // [s][hd]  16B-chunk ^ (row&15)
  __shared__ u16 Vt[128 * 64];       // [hd][s]  16B-chunk ^ (row&7)
  __shared__ u16 Ps[4][32 * 64];     // per-wave P tile, chunk ^ (row&7)
  int tid = threadIdx.x, lane = tid & 63, wid = tid >> 6;
  int quad = lane >> 4, l16 = lane & 15;
  int bx = blockIdx.x;
  int qi = 15 - (bx >> 5);           // global longest-first (q-tile = 128 rows)
  int hb = bx & 31;
  int h = hb & 15, b = hb >> 4;
  int kvh = h >> 2;                  // G = 4
  int q0 = qi * 128;
  int NT = 2 * qi + 2;               // kv tiles covering rows q0..q0+127
  int ktd = 2 * qi + (wid >> 1);     // this wave's diagonal tile

  // Q fragments: wave covers rows q0 + wid*32 .. +31 (m = 0,1)
  short8 qf[2][4];
#pragma unroll
  for (int m = 0; m < 2; m++) {
    const u16* qb = qr + ((size_t)(b * S_ + q0 + wid * 32 + m * 16 + l16) * H_ + h) * HD_;
#pragma unroll
    for (int kk = 0; kk < 4; kk++)
      qf[m][kk] = *(const short8*)(qb + kk * 32 + quad * 8);
  }

  // staging (256 threads): K row = j*16 + (tid>>4), slot = tid&15;
  // V row = j*32 + (tid>>3), slot = tid&7.  row&mask j-invariant.
  int gjk = (tid & 15) ^ ((tid >> 4) & 15);
  int gjv = (tid & 7) ^ ((tid >> 3) & 7);
  const u16* kp = kr + ((size_t)(b * S_ + (tid >> 4)) * KVH_ + kvh) * HD_ + gjk * 8;
  const u16* vp = vt + ((size_t)(b * KVH_ + kvh) * HD_ + (tid >> 3)) * S_ + gjv * 8;

  short8 pk[4], pv[4];
#pragma unroll
  for (int j = 0; j < 4; j++) {
    pk[j] = *(const short8*)(kp + (size_t)(j * 16) * KVH_ * HD_);
    pv[j] = *(const short8*)(vp + (size_t)(j * 32) * S_);
  }

  floatx4 accO[2][8] = {};
  float lp[2][4] = {};
  u16* PsW = &Ps[wid][0];

  const float LOG2E = 1.4426950408889634f;
  const float MBIAS = -12.5f * 1.4426950408889634f;

  for (int kt = 0; kt < NT; kt++) {
    int k0 = kt * 64;
#pragma unroll
    for (int j = 0; j < 4; j++) {
      *(short8*)&Ks[(j * 256 + tid) * 8] = pk[j];
      *(short8*)&Vt[(j * 256 + tid) * 8] = pv[j];
    }
    __syncthreads();

    if (kt + 1 < NT) {
      kp += (size_t)64 * KVH_ * HD_;
      vp += 64;
#pragma unroll
      for (int j = 0; j < 4; j++) {
        pk[j] = *(const short8*)(kp + (size_t)(j * 16) * KVH_ * HD_);
        pv[j] = *(const short8*)(vp + (size_t)(j * 32) * S_);
      }
    }

    if (kt <= ktd) {                 // wave-uniform; skip fully-masked tiles
      floatx4 sacc[2][4] = {};
      __builtin_amdgcn_s_setprio(1);
#pragma unroll
      for (int kk = 0; kk < 4; kk++) {
        short8 kf[4];
#pragma unroll
        for (int nt = 0; nt < 4; nt++) {
          int row = nt * 16 + l16;
          kf[nt] = *(const short8*)&Ks[row * 128 + (((kk * 4 + quad) ^ (row & 15)) * 8)];
        }
#pragma unroll
        for (int nt = 0; nt < 4; nt++) {
          sacc[0][nt] = __builtin_amdgcn_mfma_f32_16x16x32_bf16(qf[0][kk], kf[nt], sacc[0][nt], 0, 0, 0);
          sacc[1][nt] = __builtin_amdgcn_mfma_f32_16x16x32_bf16(qf[1][kk], kf[nt], sacc[1][nt], 0, 0, 0);
        }
      }
      __builtin_amdgcn_s_setprio(0);

      bool diag = (kt == ktd);
#pragma unroll
      for (int m = 0; m < 2; m++)
#pragma unroll
        for (int r = 0; r < 4; r++) {
          int prow = m * 16 + quad * 4 + r;
          int qrow = q0 + wid * 32 + prow;
          float rsum = 0.f;
#pragma unroll
          for (int nt = 0; nt < 4; nt++) {
            float p = __builtin_amdgcn_exp2f(fmaf(sacc[m][nt][r], LOG2E, MBIAS));
            if (diag && (k0 + nt * 16 + l16) > qrow) p = 0.f;
            rsum += p;
            // element (prow, col=nt*16+l16): chunk = col>>3, slot = chunk^(prow&7)
            PsW[prow * 64 + (((nt * 2 + (l16 >> 3)) ^ (prow & 7)) * 8) + (l16 & 7)] = f2bf(p);
          }
          lp[m][r] += rsum;
        }

      __builtin_amdgcn_s_setprio(1);
#pragma unroll
      for (int kk = 0; kk < 2; kk++) {
        short8 pf[2];
#pragma unroll
        for (int m = 0; m < 2; m++) {
          int prow = m * 16 + l16;
          pf[m] = *(const short8*)&PsW[prow * 64 + (((kk * 4 + quad) ^ (prow & 7)) * 8)];
        }
#pragma unroll
        for (int ht = 0; ht < 8; ht++) {
          int row = ht * 16 + l16;
          short8 vf = *(const short8*)&Vt[row * 64 + (((kk * 4 + quad) ^ (row & 7)) * 8)];
          accO[0][ht] = __builtin_amdgcn_mfma_f32_16x16x32_bf16(pf[0], vf, accO[0][ht], 0, 0, 0);
          accO[1][ht] = __builtin_amdgcn_mfma_f32_16x16x32_bf16(pf[1], vf, accO[1][ht], 0, 0, 0);
        }
      }
      __builtin_amdgcn_s_setprio(0);
    }
    __syncthreads();
  }

#pragma unroll
  for (int m = 0; m < 2; m++)
#pragma unroll
    for (int r = 0; r < 4; r++) {
#pragma unroll
      for (int d = 1; d < 16; d <<= 1) lp[m][r] += __shfl_xor(lp[m][r], d);
      lp[m][r] = 1.0f / lp[m][r];
    }

#pragma unroll
  for (int m = 0; m < 2; m++)
#pragma unroll
    for (int ht = 0; ht < 8; ht++)
#pragma unroll
      for (int r = 0; r < 4; r++) {
        int row = q0 + wid * 32 + m * 16 + quad * 4 + r;
        att[((size_t)(b * S_ + row) * H_ + h) * HD_ + ht * 16 + l16] =
            f2bf(accO[m][ht][r] * lp[m][r]);
      }
}

// ---------------------------------------------------------------------------
extern "C" void kernel_launch(void* const* d_in, const int* in_sizes, int n_in,
                              void* d_out, int out_size, void* d_ws, size_t ws_size,
                              hipStream_t stream)
{
  const float* x  = (const float*)d_in[0];   // [B,S,DM] f32
  const float* wq = (const float*)d_in[1];   // [DM, H*HD] f32
  const float* wk = (const float*)d_in[2];   // [DM, KV*HD] f32
  const float* wv = (const float*)d_in[3];   // [DM, KV*HD] f32
  const float* wo = (const float*)d_in[4];   // [H*HD, DM] f32
  const float* qs = (const float*)d_in[5];   // [HD] f32
  const float* ks = (const float*)d_in[6];   // [HD] f32

  char* ws = (char*)d_ws;
  size_t off = 0;
  u16* x_bf   = (u16*)(ws + off); off += (size_t)4096 * 2048 * 2;   // x bf16
  u16* wqkv_t = (u16*)(ws + off); off += (size_t)3072 * 2048 * 2;   // [3072][2048]
  u16* wo_t   = (u16*)(ws + off); off += (size_t)2048 * 2048 * 2;   // [2048][2048]
  u16* C1     = (u16*)(ws + off); off += (size_t)4096 * 3072 * 2;   // qkv bf16
  u16* q_rope = (u16*)(ws + off); off += (size_t)4096 * 16 * 128 * 2;
  u16* k_rope = (u16*)(ws + off); off += (size_t)4096 * 4 * 128 * 2;
  u16* vt     = (u16*)(ws + off); off += (size_t)8 * 128 * 2048 * 2;
  u16* att    = (u16*)(ws + off); off += (size_t)4096 * 2048 * 2;

  // pack x + all weight transposes, one launch
  k_prep<<<dim3(18432), 256, 0, stream>>>(x, wq, wk, wv, wo, x_bf, wqkv_t, wo_t);

  // qkv = x @ [wq|wk|wv]  (bf16 out)
  k_gemm_bt<<<dim3(24, 32), 256, 0, stream>>>(x_bf, wqkv_t, C1, 4096, 3072, 2048, 1);

  // rmsnorm+rope + v-transpose, one launch
  k_post<<<dim3(6144), 256, 0, stream>>>(C1, qs, ks, q_rope, k_rope, vt);

  // causal flash: 512 blocks x 4 waves (128 q-rows/block), longest-first
  k_flash<<<dim3(512), 256, 0, stream>>>(q_rope, k_rope, vt, att);

  // out = att @ wo  (f32 out, matching reference output dtype)
  k_gemm_bt<<<dim3(16, 32), 256, 0, stream>>>(att, wo_t, d_out, 4096, 2048, 2048, 0);

  (void)in_sizes; (void)n_in; (void)out_size; (void)ws_size;
}

// Round 3
// 290.925 us; speedup vs baseline: 1.1565x; 1.0413x over previous
//
#include <hip/hip_runtime.h>
#include <hip/hip_bf16.h>
#include <math.h>

typedef unsigned short u16;
typedef short short8 __attribute__((ext_vector_type(8)));
typedef float floatx4 __attribute__((ext_vector_type(4)));

#define B_   2
#define S_   2048
#define DM_  2048
#define H_   16
#define KVH_ 4
#define HD_  128

__device__ __forceinline__ float bf2f(u16 v) {
  union { unsigned int u; float f; } x; x.u = ((unsigned int)v) << 16; return x.f;
}
__device__ __forceinline__ u16 f2bf(float f) {
  union { float f; unsigned int u; } x; x.f = f;
  unsigned int u = x.u;
  u += 0x7FFFu + ((u >> 16) & 1u);   // RNE; inputs finite
  return (u16)(u >> 16);
}

// async 16B global->LDS (lds dest = wave-uniform base + lane*16)
#define GLDS16(gp, lp) __builtin_amdgcn_global_load_lds( \
    (const __attribute__((address_space(1))) unsigned int*)(const void*)(gp), \
    (__attribute__((address_space(3))) unsigned int*)(void*)(lp), 16, 0, 0)

// ---------------------------------------------------------------------------
// k_prep: pack_x (blocks 0..8191) + 4 weight transposes (blocks 8192..18431)
// merged into one launch (block-uniform branching).
// ---------------------------------------------------------------------------
__global__ __launch_bounds__(256) void k_prep(
    const float* __restrict__ x, const float* __restrict__ wq,
    const float* __restrict__ wk, const float* __restrict__ wv,
    const float* __restrict__ wo,
    u16* __restrict__ x_bf, u16* __restrict__ wqkv_t, u16* __restrict__ wo_t)
{
  int bx = blockIdx.x;
  if (bx < 8192) {                       // x -> bf16, 4 elems/thread
    int i = bx * 256 + threadIdx.x;
    const float4 v = ((const float4*)x)[i];
    u16 o[4] = { f2bf(v.x), f2bf(v.y), f2bf(v.z), f2bf(v.w) };
    *(unsigned long long*)(x_bf + (size_t)i * 4) = *(unsigned long long*)o;
    return;
  }
  bx -= 8192;
  const float* src; u16* dst; int C, cb;
  if (bx < 4096)      { src = wq; dst = wqkv_t; C = 2048; cb = 64; }
  else if (bx < 5120) { bx -= 4096; src = wk; dst = wqkv_t + (size_t)2048 * 2048; C = 512; cb = 16; }
  else if (bx < 6144) { bx -= 5120; src = wv; dst = wqkv_t + (size_t)2560 * 2048; C = 512; cb = 16; }
  else                { bx -= 6144; src = wo; dst = wo_t; C = 2048; cb = 64; }
  const int R = 2048;
  int c0 = (bx % cb) * 32, r0 = (bx / cb) * 32;
  __shared__ float tile[32][33];
  int tx = threadIdx.x & 31, ty = threadIdx.x >> 5;
#pragma unroll
  for (int j = 0; j < 4; j++)
    tile[ty * 4 + j][tx] = src[(size_t)(r0 + ty * 4 + j) * C + c0 + tx];
  __syncthreads();
#pragma unroll
  for (int j = 0; j < 4; j++)
    dst[(size_t)(c0 + ty * 4 + j) * R + r0 + tx] = f2bf(tile[tx][ty * 4 + j]);
}

// ---------------------------------------------------------------------------
// GEMM: C[M][N] = A[M][K] * Bt[N][K]^T   (bf16 in, f32 accum, f32/bf16 out)
// 128x128 tile, BK=64 (32 KB LDS): 32 MFMA per barrier pair (AITER ratio).
// LDS row = 8 chunks of 16B; swizzle chunk ^ (row&7) kills bank conflicts.
// ---------------------------------------------------------------------------
__global__ __launch_bounds__(256, 3) void k_gemm_bt(
    const u16* __restrict__ A, const u16* __restrict__ Bt,
    void* __restrict__ Cout, int M, int N, int K, int c_bf16)
{
  __shared__ u16 As[128 * 64];
  __shared__ u16 Bs[128 * 64];
  int tid = threadIdx.x;
  int lane = tid & 63;
  int quad = lane >> 4, l16 = lane & 15;
  int wid = tid >> 6;
  int m0 = blockIdx.y * 128, n0 = blockIdx.x * 128;
  int wm = (wid >> 1) * 64, wn = (wid & 1) * 64;

  floatx4 acc[4][4] = {};

  // staging: c = j*256 + tid -> row = c>>3 (j adds 32 rows; row&7 invariant),
  // LDS chunkpos = c&7 holds global chunk (c&7) ^ (row&7)
  int srow = tid >> 3;
  int gjc0 = (tid & 7) ^ (srow & 7);
  const u16* Ap = A + (size_t)(m0 + srow) * K + gjc0 * 8;
  const u16* Bp = Bt + (size_t)(n0 + srow) * K + gjc0 * 8;
  u16* AsW = As + tid * 8;
  u16* BsW = Bs + tid * 8;

  for (int kt = 0; kt < K; kt += 64) {
    __syncthreads();                     // protect LDS from prev iter readers
#pragma unroll
    for (int j = 0; j < 4; j++) {
      GLDS16(Ap + (size_t)(j * 32) * K, AsW + j * 2048);
      GLDS16(Bp + (size_t)(j * 32) * K, BsW + j * 2048);
    }
    Ap += 64; Bp += 64;
    __syncthreads();                     // drains vmcnt(0)

#pragma unroll
    for (int ks = 0; ks < 2; ks++) {
      short8 af[4], bfv[4];
#pragma unroll
      for (int mi = 0; mi < 4; mi++) {
        int row = wm + mi * 16 + l16;
        af[mi] = *(const short8*)&As[row * 64 + (((ks * 4 + quad) ^ (row & 7)) * 8)];
      }
#pragma unroll
      for (int ni = 0; ni < 4; ni++) {
        int row = wn + ni * 16 + l16;
        bfv[ni] = *(const short8*)&Bs[row * 64 + (((ks * 4 + quad) ^ (row & 7)) * 8)];
      }
#pragma unroll
      for (int mi = 0; mi < 4; mi++)
#pragma unroll
        for (int ni = 0; ni < 4; ni++)
          acc[mi][ni] = __builtin_amdgcn_mfma_f32_16x16x32_bf16(
              af[mi], bfv[ni], acc[mi][ni], 0, 0, 0);
    }
  }

#pragma unroll
  for (int mi = 0; mi < 4; mi++)
#pragma unroll
    for (int ni = 0; ni < 4; ni++)
#pragma unroll
      for (int r = 0; r < 4; r++) {
        int row = m0 + wm + mi * 16 + quad * 4 + r;
        int col = n0 + wn + ni * 16 + l16;
        float v = acc[mi][ni][r];
        if (c_bf16) ((u16*)Cout)[(size_t)row * N + col] = f2bf(v);
        else        ((float*)Cout)[(size_t)row * N + col] = v;
      }
}

// ---------------------------------------------------------------------------
// k_post: RMSNorm+RoPE (blocks 0..4095) + pack_vt (blocks 4096..6143) merged.
// ---------------------------------------------------------------------------
__global__ __launch_bounds__(256) void k_post(
    const u16* __restrict__ C1, const float* __restrict__ qs,
    const float* __restrict__ ks, u16* __restrict__ qr, u16* __restrict__ kr,
    u16* __restrict__ vt)
{
  int bx = blockIdx.x;
  if (bx < 4096) {                       // rmsnorm + rope
    int m = bx;
    int lane = threadIdx.x & 63, wid = threadIdx.x >> 6;
    int pos = m & (S_ - 1);
    float ts = powf(10000.0f, (float)lane * (1.0f / 64.0f));
    float ang = (float)pos / ts;
    float sn = sinf(ang), cs = cosf(ang);
    for (int r = wid; r < H_ + KVH_; r += 4) {
      bool isq = r < H_;
      const u16* src = C1 + (size_t)m * 3072 + (isq ? r * HD_ : DM_ + (r - H_) * HD_);
      float x1 = bf2f(src[lane]), x2 = bf2f(src[lane + 64]);
      float ss = x1 * x1 + x2 * x2;
#pragma unroll
      for (int d = 1; d < 64; d <<= 1) ss += __shfl_xor(ss, d);
      float rs = rsqrtf(ss * (1.0f / 128.0f) + 1e-6f);
      const float* sc = isq ? qs : ks;
      float y1 = x1 * rs * sc[lane];
      float y2 = x2 * rs * sc[lane + 64];
      float o1 = y1 * cs - y2 * sn;
      float o2 = y2 * cs + y1 * sn;
      if (isq) { o1 *= 0.088388347648318447f; o2 *= 0.088388347648318447f; }
      u16* dst = isq ? (qr + ((size_t)m * H_ + r) * HD_)
                     : (kr + ((size_t)m * KVH_ + (r - H_)) * HD_);
      dst[lane]      = f2bf(o1);
      dst[lane + 64] = f2bf(o2);
    }
    return;
  }
  bx -= 4096;                            // pack_vt: decode 64 x 4 x 8
  int sx = bx & 63, rest = bx >> 6;
  int hy = rest & 3, bk = rest >> 2;
  int s0 = sx * 32, h0 = hy * 32;
  int b = bk >> 2, kv = bk & 3;
  __shared__ u16 tile[32][33];
  int tx = threadIdx.x & 31, ty = threadIdx.x >> 5;
#pragma unroll
  for (int j = 0; j < 4; j++)
    tile[ty * 4 + j][tx] =
        C1[(size_t)(b * S_ + s0 + ty * 4 + j) * 3072 + 2560 + kv * HD_ + h0 + tx];
  __syncthreads();
#pragma unroll
  for (int j = 0; j < 4; j++)
    vt[((size_t)bk * HD_ + h0 + ty * 4 + j) * S_ + s0 + tx] = tile[tx][ty * 4 + j];
}

// ---------------------------------------------------------------------------
// Flash attention v4: 1024 blocks x 4 waves, 64 q-rows/block (v1 balance),
// global_load_lds DOUBLE-BUFFERED staging (T3 minimum 2-phase: 1 barrier per
// kv-tile, zero ds_write staging, -32 VGPR), waves split (row-half, s-half):
//   wave w: q-rows (w&1)*32..+31, s-cols (w>>1)*32..+31 of each kv-tile.
// Each wave computes QK + softmax + PV over its own s-half only (Ps stays
// wave-private, no mid barrier); partial accO / lp combined once in epilogue.
// FIXED-MAX softmax (Cauchy-Schwarz bound |score| <= 11.32 post-RMSNorm).
// LDS: 2x16K (K dbuf) + 2x16K (V dbuf) + 12K (Ps 4x[32][48]) + 0.5K = 78.3KB
// -> 2 blocks/CU, 8 waves/CU.
// ---------------------------------------------------------------------------
__global__ __launch_bounds__(256, 2) void k_flash(
    const u16* __restrict__ qr, const u16* __restrict__ kr,
    const u16* __restrict__ vt, u16* __restrict__ att)
{
  // layout (u16 units): Ks[2] @0 (2x8192), Vt[2] @16384 (2x8192),
  // Ps @32768 (4x1536), lpbuf @38912 (64 floats used)
  __shared__ u16 smem[39168] __attribute__((aligned(16)));
  u16* Ps = smem + 32768;
  float* lpbuf = (float*)(smem + 38912);

  int tid = threadIdx.x, lane = tid & 63, wid = tid >> 6;
  int quad = lane >> 4, l16 = lane & 15;
  int rhalf = wid & 1;               // q-row half (0: rows 0-31, 1: 32-63)
  int shalf = wid >> 1;              // s-col half of each kv tile
  int bx = blockIdx.x;
  int it = 31 - (bx >> 5);           // global longest-first (64-row q tiles)
  int hb = bx & 31;
  int h = hb & 15, b = hb >> 4;
  int kvh = h >> 2;                  // G = 4
  int q0 = it * 64;
  int NT = it + 1;

  // Q fragments: wave rows q0 + rhalf*32 + m*16 + l16
  short8 qf[2][4];
#pragma unroll
  for (int m = 0; m < 2; m++) {
    const u16* qb = qr + ((size_t)(b * S_ + q0 + rhalf * 32 + m * 16 + l16) * H_ + h) * HD_;
#pragma unroll
    for (int kk = 0; kk < 4; kk++)
      qf[m][kk] = *(const short8*)(qb + kk * 32 + quad * 8);
  }

  // staging sources (pre-swizzled global chunk so LDS stays linear, m173):
  // K: flat chunk c = j*256+tid -> row = c>>4 = j*16 + (tid>>4), slot = tid&15
  //    stored slot s holds global chunk s ^ (row&15)
  // V: row = j*32 + (tid>>3), slot = tid&7, global chunk = slot ^ (row&7)
  int gjk = (tid & 15) ^ ((tid >> 4) & 15);
  int gjv = (tid & 7) ^ ((tid >> 3) & 7);
  const u16* kp = kr + ((size_t)(b * S_ + (tid >> 4)) * KVH_ + kvh) * HD_ + gjk * 8;
  const u16* vp = vt + ((size_t)(b * KVH_ + kvh) * HD_ + (tid >> 3)) * S_ + gjv * 8;

  // prologue: stage tile 0 into buffer 0
#pragma unroll
  for (int j = 0; j < 4; j++) {
    GLDS16(kp + (size_t)(j * 16) * KVH_ * HD_, smem + (size_t)(j * 256 + tid) * 8);
    GLDS16(vp + (size_t)(j * 32) * S_,         smem + 16384 + (size_t)(j * 256 + tid) * 8);
  }
  kp += (size_t)64 * KVH_ * HD_;
  vp += 64;
  __syncthreads();                   // drains vmcnt(0): tile 0 ready

  floatx4 accO[2][8] = {};           // partial O: full d, own s-half
  float lp[2][4] = {};               // partial denominators, own s-half
  u16* PsW = Ps + wid * 1536;        // [32 rows][48 cols], 32 data cols

  const float LOG2E = 1.4426950408889634f;
  const float MBIAS = -12.5f * 1.4426950408889634f;
  int qmax = q0 + rhalf * 32 + 31;

  for (int kt = 0; kt < NT; kt++) {
    // async: issue next tile into the other buffer (lands by next barrier)
    if (kt + 1 < NT) {
      u16* KD = smem + (size_t)((kt + 1) & 1) * 8192;
      u16* VD = smem + 16384 + (size_t)((kt + 1) & 1) * 8192;
#pragma unroll
      for (int j = 0; j < 4; j++) {
        GLDS16(kp + (size_t)(j * 16) * KVH_ * HD_, KD + (size_t)(j * 256 + tid) * 8);
        GLDS16(vp + (size_t)(j * 32) * S_,         VD + (size_t)(j * 256 + tid) * 8);
      }
      kp += (size_t)64 * KVH_ * HD_;
      vp += 64;
    }

    int k0 = kt * 64;
    int s0w = k0 + shalf * 32;       // this wave's first s col
    if (s0w <= qmax) {               // wave-uniform skip of fully-masked tiles
      const u16* KsC = smem + (size_t)(kt & 1) * 8192;
      const u16* VtC = smem + 16384 + (size_t)(kt & 1) * 8192;

      // QK^T over own s-half: sacc[m][nt], rows m*16+quad*4+r, cols nt*16+l16
      floatx4 sacc[2][2] = {};
      __builtin_amdgcn_s_setprio(1);
#pragma unroll
      for (int kk = 0; kk < 4; kk++) {
        short8 kf[2];
#pragma unroll
        for (int nt = 0; nt < 2; nt++) {
          int row = shalf * 32 + nt * 16 + l16;
          kf[nt] = *(const short8*)&KsC[row * 128 + (((kk * 4 + quad) ^ (row & 15)) * 8)];
        }
#pragma unroll
        for (int nt = 0; nt < 2; nt++) {
          sacc[0][nt] = __builtin_amdgcn_mfma_f32_16x16x32_bf16(qf[0][kk], kf[nt], sacc[0][nt], 0, 0, 0);
          sacc[1][nt] = __builtin_amdgcn_mfma_f32_16x16x32_bf16(qf[1][kk], kf[nt], sacc[1][nt], 0, 0, 0);
        }
      }
      __builtin_amdgcn_s_setprio(0);

      // softmax (fixed max) + Ps write.  Ps col swizzle: 4 chunks of 8,
      // stored chunk = (col>>3) ^ ((row>>2)&1); (row>>2)&1 == quad&1 here.
      bool diag = (s0w + 31 > q0 + rhalf * 32);
#pragma unroll
      for (int m = 0; m < 2; m++)
#pragma unroll
        for (int r = 0; r < 4; r++) {
          int prow = m * 16 + quad * 4 + r;
          int qrow = q0 + rhalf * 32 + prow;
          float rsum = 0.f;
#pragma unroll
          for (int nt = 0; nt < 2; nt++) {
            float p = __builtin_amdgcn_exp2f(fmaf(sacc[m][nt][r], LOG2E, MBIAS));
            if (diag && (s0w + nt * 16 + l16) > qrow) p = 0.f;
            rsum += p;
            int chunk = nt * 2 + (l16 >> 3);
            PsW[prow * 48 + ((chunk ^ (quad & 1)) * 8) + (l16 & 7)] = f2bf(p);
          }
          lp[m][r] += rsum;
        }

      // PV over own s-half (k=32 = one MFMA K): accO[m][ht] full d
      __builtin_amdgcn_s_setprio(1);
      short8 pf[2];
#pragma unroll
      for (int m = 0; m < 2; m++) {
        int prow = m * 16 + l16;     // (prow>>2)&1 == (l16>>2)&1
        pf[m] = *(const short8*)&PsW[prow * 48 + ((quad ^ ((l16 >> 2) & 1)) * 8)];
      }
#pragma unroll
      for (int ht = 0; ht < 8; ht++) {
        int row = ht * 16 + l16;
        short8 vf = *(const short8*)&VtC[row * 64 + (((shalf * 4 + quad) ^ (row & 7)) * 8)];
        accO[0][ht] = __builtin_amdgcn_mfma_f32_16x16x32_bf16(pf[0], vf, accO[0][ht], 0, 0, 0);
        accO[1][ht] = __builtin_amdgcn_mfma_f32_16x16x32_bf16(pf[1], vf, accO[1][ht], 0, 0, 0);
      }
      __builtin_amdgcn_s_setprio(0);
    }
    __syncthreads();                 // readers done + next tile's GLDS drained
  }

  // reduce lp across l16 (within quad -> per-row partial sums)
#pragma unroll
  for (int m = 0; m < 2; m++)
#pragma unroll
    for (int r = 0; r < 4; r++) {
#pragma unroll
      for (int d = 1; d < 16; d <<= 1) lp[m][r] += __shfl_xor(lp[m][r], d);
    }

  // combine wave w (s-half 0) with wave w+2 (s-half 1) via LDS overlay
  floatx4* xch = (floatx4*)(void*)smem;          // 32 KB overlay on K/V dbuf
  if (wid >= 2) {
    floatx4* dst = xch + ((wid & 1) * 1024 + lane * 16);
#pragma unroll
    for (int m = 0; m < 2; m++)
#pragma unroll
      for (int ht = 0; ht < 8; ht++) dst[m * 8 + ht] = accO[m][ht];
    if (l16 == 0) {
#pragma unroll
      for (int m = 0; m < 2; m++)
#pragma unroll
        for (int r = 0; r < 4; r++)
          lpbuf[(wid & 1) * 32 + m * 16 + quad * 4 + r] = lp[m][r];
    }
  }
  __syncthreads();
  if (wid < 2) {
    floatx4* src = xch + (wid * 1024 + lane * 16);
    float inv[2][4];
#pragma unroll
    for (int m = 0; m < 2; m++)
#pragma unroll
      for (int ht = 0; ht < 8; ht++) accO[m][ht] += src[m * 8 + ht];
#pragma unroll
    for (int m = 0; m < 2; m++)
#pragma unroll
      for (int r = 0; r < 4; r++)
        inv[m][r] = 1.0f / (lp[m][r] + lpbuf[wid * 32 + m * 16 + quad * 4 + r]);
#pragma unroll
    for (int m = 0; m < 2; m++)
#pragma unroll
      for (int ht = 0; ht < 8; ht++)
#pragma unroll
        for (int r = 0; r < 4; r++) {
          int row = q0 + wid * 32 + m * 16 + quad * 4 + r;
          att[((size_t)(b * S_ + row) * H_ + h) * HD_ + ht * 16 + l16] =
              f2bf(accO[m][ht][r] * inv[m][r]);
        }
  }
}

// ---------------------------------------------------------------------------
extern "C" void kernel_launch(void* const* d_in, const int* in_sizes, int n_in,
                              void* d_out, int out_size, void* d_ws, size_t ws_size,
                              hipStream_t stream)
{
  const float* x  = (const float*)d_in[0];   // [B,S,DM] f32
  const float* wq = (const float*)d_in[1];   // [DM, H*HD] f32
  const float* wk = (const float*)d_in[2];   // [DM, KV*HD] f32
  const float* wv = (const float*)d_in[3];   // [DM, KV*HD] f32
  const float* wo = (const float*)d_in[4];   // [H*HD, DM] f32
  const float* qs = (const float*)d_in[5];   // [HD] f32
  const float* ks = (const float*)d_in[6];   // [HD] f32

  char* ws = (char*)d_ws;
  size_t off = 0;
  u16* x_bf   = (u16*)(ws + off); off += (size_t)4096 * 2048 * 2;   // x bf16
  u16* wqkv_t = (u16*)(ws + off); off += (size_t)3072 * 2048 * 2;   // [3072][2048]
  u16* wo_t   = (u16*)(ws + off); off += (size_t)2048 * 2048 * 2;   // [2048][2048]
  u16* C1     = (u16*)(ws + off); off += (size_t)4096 * 3072 * 2;   // qkv bf16
  u16* q_rope = (u16*)(ws + off); off += (size_t)4096 * 16 * 128 * 2;
  u16* k_rope = (u16*)(ws + off); off += (size_t)4096 * 4 * 128 * 2;
  u16* vt     = (u16*)(ws + off); off += (size_t)8 * 128 * 2048 * 2;
  u16* att    = (u16*)(ws + off); off += (size_t)4096 * 2048 * 2;

  // pack x + all weight transposes, one launch
  k_prep<<<dim3(18432), 256, 0, stream>>>(x, wq, wk, wv, wo, x_bf, wqkv_t, wo_t);

  // qkv = x @ [wq|wk|wv]  (bf16 out)
  k_gemm_bt<<<dim3(24, 32), 256, 0, stream>>>(x_bf, wqkv_t, C1, 4096, 3072, 2048, 1);

  // rmsnorm+rope + v-transpose, one launch
  k_post<<<dim3(6144), 256, 0, stream>>>(C1, qs, ks, q_rope, k_rope, vt);

  // causal flash: 1024 blocks x 4 waves (64 q-rows/block), longest-first
  k_flash<<<dim3(1024), 256, 0, stream>>>(q_rope, k_rope, vt, att);

  // out = att @ wo  (f32 out, matching reference output dtype)
  k_gemm_bt<<<dim3(16, 32), 256, 0, stream>>>(att, wo_t, d_out, 4096, 2048, 2048, 0);

  (void)in_sizes; (void)n_in; (void)out_size; (void)ws_size;
}